// Round 1
// baseline (2172.111 us; speedup 1.0000x reference)
//
#include <hip/hip_runtime.h>

#define NN 50000
#define NE 1600000
#define DD 128
#define NLAYERS 6
#define NG 8
#define BN_EPS 1e-5f

// ---------------- CSR build ----------------

__global__ void k_hist(const int* __restrict__ dst, int* __restrict__ deg) {
    for (int e = blockIdx.x * blockDim.x + threadIdx.x; e < NE; e += gridDim.x * blockDim.x)
        atomicAdd(&deg[dst[e]], 1);
}

__global__ __launch_bounds__(1024) void k_scan(const int* __restrict__ deg,
                                               int* __restrict__ off,
                                               int* __restrict__ cur) {
    __shared__ int part[1024];
    int t = threadIdx.x;
    const int CH = (NN + 1023) / 1024;  // 49
    int lo = t * CH, hi = lo + CH; if (hi > NN) hi = NN; if (lo > NN) lo = NN;
    int s = 0;
    for (int i = lo; i < hi; ++i) s += deg[i];
    part[t] = s;
    __syncthreads();
    for (int d = 1; d < 1024; d <<= 1) {
        int v = (t >= d) ? part[t - d] : 0;
        __syncthreads();
        part[t] += v;
        __syncthreads();
    }
    int run = (t == 0) ? 0 : part[t - 1];
    for (int i = lo; i < hi; ++i) {
        off[i] = run; cur[i] = run;
        run += deg[i];
    }
    if (t == 0) off[NN] = NE;
}

__global__ void k_scatter(const int* __restrict__ src, const int* __restrict__ dst,
                          int* __restrict__ cur, int* __restrict__ csr) {
    for (int e = blockIdx.x * blockDim.x + threadIdx.x; e < NE; e += gridDim.x * blockDim.x) {
        int d = dst[e];
        int p = atomicAdd(&cur[d], 1);
        csr[p] = src[e];
    }
}

__global__ void k_init_st(float* __restrict__ st) {
    int t = threadIdx.x;
    st[t] = (t < DD) ? 1.f : 0.f;
}

// ---------------- aggregation: one wave per dst node ----------------
// agg'[n][c] = s[c] * sum_{j in N(n)} hraw[j][c] + t[c] * deg(n)

__global__ __launch_bounds__(256) void k_agg(const float* __restrict__ h,
                                             const int* __restrict__ off,
                                             const int* __restrict__ csr,
                                             const float* __restrict__ st,
                                             float* __restrict__ agg) {
    int w = (blockIdx.x * blockDim.x + threadIdx.x) >> 6;
    int lane = threadIdx.x & 63;
    if (w >= NN) return;
    int lo = off[w], hi = off[w + 1];
    const float2* hp = (const float2*)h;
    float2 acc = make_float2(0.f, 0.f);
    int e = lo;
    for (; e + 4 <= hi; e += 4) {
        int s0 = csr[e], s1 = csr[e + 1], s2 = csr[e + 2], s3 = csr[e + 3];
        float2 v0 = hp[(size_t)s0 * 64 + lane];
        float2 v1 = hp[(size_t)s1 * 64 + lane];
        float2 v2 = hp[(size_t)s2 * 64 + lane];
        float2 v3 = hp[(size_t)s3 * 64 + lane];
        acc.x += (v0.x + v1.x) + (v2.x + v3.x);
        acc.y += (v0.y + v1.y) + (v2.y + v3.y);
    }
    for (; e < hi; ++e) {
        int s = csr[e];
        float2 v = hp[(size_t)s * 64 + lane];
        acc.x += v.x; acc.y += v.y;
    }
    float degf = (float)(hi - lo);
    int c = lane * 2;
    float2 o;
    o.x = fmaf(st[c],     acc.x, st[DD + c]     * degf);
    o.y = fmaf(st[c + 1], acc.y, st[DD + c + 1] * degf);
    ((float2*)agg)[(size_t)w * 64 + lane] = o;
}

// ---------------- fused dual GEMM + bias + relu ----------------
// hout = relu( agg' @ Wrel + (s*hraw + t) @ Wroot + brel ), raw relu stored

__global__ __launch_bounds__(256) void k_gemm(const float* __restrict__ agg,
                                              const float* __restrict__ hraw,
                                              const float* __restrict__ st,
                                              const float* __restrict__ Wrel,
                                              const float* __restrict__ Wroot,
                                              const float* __restrict__ brel,
                                              float* __restrict__ hout) {
    __shared__ float As[64][132];
    __shared__ float Bs[64][64];
    const int tid = threadIdx.x;
    const int tx = tid & 15, ty = tid >> 4;
    const int n0 = blockIdx.x * 64;
    const int c0 = blockIdx.y * 64;
    float acc[4][4] = {};
    for (int pass = 0; pass < 2; ++pass) {
        const float* A = pass ? hraw : agg;
        const float* W = pass ? Wroot : Wrel;
        if (pass) __syncthreads();  // protect As reads from pass 0
#pragma unroll
        for (int rep = 0; rep < 8; ++rep) {
            int r = rep * 8 + (tid >> 5);
            int kq = (tid & 31) * 4;
            int n = n0 + r;
            float4 v = make_float4(0.f, 0.f, 0.f, 0.f);
            if (n < NN) v = *(const float4*)(A + (size_t)n * DD + kq);
            if (pass) {
                float4 s4 = *(const float4*)(st + kq);
                float4 t4 = *(const float4*)(st + DD + kq);
                v.x = fmaf(s4.x, v.x, t4.x);
                v.y = fmaf(s4.y, v.y, t4.y);
                v.z = fmaf(s4.z, v.z, t4.z);
                v.w = fmaf(s4.w, v.w, t4.w);
            }
            *(float4*)(&As[r][kq]) = v;
        }
        for (int kc = 0; kc < DD; kc += 64) {
            __syncthreads();  // As ready / previous Bs reads done
#pragma unroll
            for (int rep = 0; rep < 4; ++rep) {
                int idx = rep * 256 + tid;
                int kl = idx >> 4;
                int j = (idx & 15) * 4;
                *(float4*)(&Bs[kl][j]) = *(const float4*)(W + (size_t)(kc + kl) * DD + c0 + j);
            }
            __syncthreads();
#pragma unroll 16
            for (int k = 0; k < 64; ++k) {
                float4 b = *(float4*)(&Bs[k][tx * 4]);
#pragma unroll
                for (int i = 0; i < 4; ++i) {
                    float a = As[ty * 4 + i][kc + k];
                    acc[i][0] = fmaf(a, b.x, acc[i][0]);
                    acc[i][1] = fmaf(a, b.y, acc[i][1]);
                    acc[i][2] = fmaf(a, b.z, acc[i][2]);
                    acc[i][3] = fmaf(a, b.w, acc[i][3]);
                }
            }
        }
    }
    float4 bias = *(const float4*)(brel + c0 + tx * 4);
#pragma unroll
    for (int i = 0; i < 4; ++i) {
        int n = n0 + ty * 4 + i;
        if (n < NN) {
            float4 o;
            o.x = fmaxf(acc[i][0] + bias.x, 0.f);
            o.y = fmaxf(acc[i][1] + bias.y, 0.f);
            o.z = fmaxf(acc[i][2] + bias.z, 0.f);
            o.w = fmaxf(acc[i][3] + bias.w, 0.f);
            *(float4*)(hout + (size_t)n * DD + c0 + tx * 4) = o;
        }
    }
}

// ---------------- column stats (sum, sumsq) ----------------

__global__ __launch_bounds__(256) void k_stats(const float* __restrict__ h,
                                               float* __restrict__ stats) {
    int c = threadIdx.x & 127;
    int r0 = blockIdx.x * 2 + (threadIdx.x >> 7);
    float s = 0.f, q = 0.f;
    for (int n = r0; n < NN; n += gridDim.x * 2) {
        float v = h[(size_t)n * DD + c];
        s += v; q += v * v;
    }
    __shared__ float ls[256], lq[256];
    ls[threadIdx.x] = s; lq[threadIdx.x] = q;
    __syncthreads();
    if (threadIdx.x < 128) {
        s = ls[threadIdx.x] + ls[threadIdx.x + 128];
        q = lq[threadIdx.x] + lq[threadIdx.x + 128];
        atomicAdd(&stats[c], s);
        atomicAdd(&stats[DD + c], q);
    }
}

__global__ void k_bn(const float* __restrict__ stats, const float* __restrict__ gamma,
                     const float* __restrict__ beta, float* __restrict__ st) {
    int c = threadIdx.x;  // 128 threads
    float mean = stats[c] * (1.0f / NN);
    float var = stats[DD + c] * (1.0f / NN) - mean * mean;
    float s = gamma[c] / sqrtf(var + BN_EPS);
    st[c] = s;
    st[DD + c] = beta[c] - mean * s;
}

// ---------------- pooling ----------------

__global__ __launch_bounds__(256) void k_pool(const float* __restrict__ h,
                                              const float* __restrict__ st,
                                              const int* __restrict__ batch,
                                              float* __restrict__ pooled,
                                              float* __restrict__ counts) {
    int node = blockIdx.x * 2 + (threadIdx.x >> 7);
    int c = threadIdx.x & 127;
    if (node >= NN) return;
    int g = batch[node];
    float v = fmaf(st[c], h[(size_t)node * DD + c], st[DD + c]);
    atomicAdd(&pooled[g * DD + c], v);
    if (c == 0) atomicAdd(&counts[g], 1.0f);
}

// ---------------- head: dense+relu then mu ----------------

__global__ __launch_bounds__(1024) void k_head(const float* __restrict__ pooled,
                                               const float* __restrict__ counts,
                                               const float* __restrict__ dw,
                                               const float* __restrict__ db,
                                               const float* __restrict__ muw,
                                               const float* __restrict__ mub,
                                               float* __restrict__ out) {
    __shared__ float pm[NG][DD];
    __shared__ float zs[NG][DD];
    int t = threadIdx.x;
    int g = t >> 7, c = t & 127;
    pm[g][c] = pooled[g * DD + c] / fmaxf(counts[g], 1.0f);
    __syncthreads();
    float acc = 0.f;
    for (int k = 0; k < DD; ++k)
        acc = fmaf(pm[g][k], dw[k * DD + c], acc);
    float z = fmaxf(acc + db[c], 0.f);
    zs[g][c] = z * muw[c];
    __syncthreads();
    if (c == 0) {
        float s = 0.f;
        for (int k = 0; k < DD; ++k) s += zs[g][k];
        out[g] = s + mub[0];
    }
}

// ---------------- host ----------------

extern "C" void kernel_launch(void* const* d_in, const int* in_sizes, int n_in,
                              void* d_out, int out_size, void* d_ws, size_t ws_size,
                              hipStream_t stream) {
    const float* x      = (const float*)d_in[0];
    const int*   ei     = (const int*)d_in[1];
    const int*   batch  = (const int*)d_in[2];
    const float* W_rel  = (const float*)d_in[3];
    const float* b_rel  = (const float*)d_in[4];
    const float* W_root = (const float*)d_in[5];
    const float* gamma  = (const float*)d_in[6];
    const float* beta   = (const float*)d_in[7];
    const float* dw     = (const float*)d_in[8];
    const float* db     = (const float*)d_in[9];
    const float* muw    = (const float*)d_in[10];
    const float* mub    = (const float*)d_in[11];
    float* out = (float*)d_out;

    char* w = (char*)d_ws;
    auto alloc = [&](size_t bytes) {
        char* p = w;
        w += (bytes + 255) & ~(size_t)255;
        return p;
    };
    int*   deg    = (int*)alloc((size_t)NN * 4);
    int*   off    = (int*)alloc((size_t)(NN + 1) * 4);
    int*   cur    = (int*)alloc((size_t)NN * 4);
    int*   csr    = (int*)alloc((size_t)NE * 4);
    float* hA     = (float*)alloc((size_t)NN * DD * 4);
    float* hB     = (float*)alloc((size_t)NN * DD * 4);
    float* aggb   = (float*)alloc((size_t)NN * DD * 4);
    float* stats  = (float*)alloc(2 * DD * 4);
    float* st     = (float*)alloc(2 * DD * 4);
    float* pooled = (float*)alloc(NG * DD * 4);
    float* counts = (float*)alloc(NG * 4);

    const int* src = ei;
    const int* dst = ei + NE;

    hipMemsetAsync(deg, 0, (size_t)NN * 4, stream);
    k_hist<<<2048, 256, 0, stream>>>(dst, deg);
    k_scan<<<1, 1024, 0, stream>>>(deg, off, cur);
    k_scatter<<<2048, 256, 0, stream>>>(src, dst, cur, csr);
    k_init_st<<<1, 256, 0, stream>>>(st);

    const float* hcur = x;
    float* bufs[2] = {hA, hB};
    for (int i = 0; i < NLAYERS; ++i) {
        float* hnext = bufs[i & 1];
        k_agg<<<(NN * 64 + 255) / 256, 256, 0, stream>>>(hcur, off, csr, st, aggb);
        k_gemm<<<dim3((NN + 63) / 64, 2), 256, 0, stream>>>(
            aggb, hcur, st, W_rel + (size_t)i * DD * DD, W_root + (size_t)i * DD * DD,
            b_rel + (size_t)i * DD, hnext);
        hipMemsetAsync(stats, 0, 2 * DD * 4, stream);
        k_stats<<<512, 256, 0, stream>>>(hnext, stats);
        k_bn<<<1, 128, 0, stream>>>(stats, gamma + (size_t)i * DD, beta + (size_t)i * DD, st);
        hcur = hnext;
    }
    hipMemsetAsync(pooled, 0, (size_t)NG * DD * 4, stream);
    hipMemsetAsync(counts, 0, (size_t)NG * 4, stream);
    k_pool<<<(NN + 1) / 2, 256, 0, stream>>>(hcur, st, batch, pooled, counts);
    k_head<<<1, 1024, 0, stream>>>(pooled, counts, dw, db, muw, mub, out);
}

// Round 2
// 1513.858 us; speedup vs baseline: 1.4348x; 1.4348x over previous
//
#include <hip/hip_runtime.h>

#define NN 50000
#define NE 1600000
#define DD 128
#define NLAYERS 6
#define NG 8
#define BN_EPS 1e-5f

// ---------------- CSR build ----------------

__global__ void k_hist(const int* __restrict__ dst, int* __restrict__ deg) {
    for (int e = blockIdx.x * blockDim.x + threadIdx.x; e < NE; e += gridDim.x * blockDim.x)
        atomicAdd(&deg[dst[e]], 1);
}

__global__ __launch_bounds__(1024) void k_scan(const int* __restrict__ deg,
                                               int* __restrict__ off,
                                               int* __restrict__ cur) {
    __shared__ int part[1024];
    int t = threadIdx.x;
    const int CH = (NN + 1023) / 1024;  // 49
    int lo = t * CH, hi = lo + CH; if (hi > NN) hi = NN; if (lo > NN) lo = NN;
    int s = 0;
    for (int i = lo; i < hi; ++i) s += deg[i];
    part[t] = s;
    __syncthreads();
    for (int d = 1; d < 1024; d <<= 1) {
        int v = (t >= d) ? part[t - d] : 0;
        __syncthreads();
        part[t] += v;
        __syncthreads();
    }
    int run = (t == 0) ? 0 : part[t - 1];
    for (int i = lo; i < hi; ++i) {
        off[i] = run; cur[i] = run;
        run += deg[i];
    }
    if (t == 0) off[NN] = NE;
}

__global__ void k_scatter(const int* __restrict__ src, const int* __restrict__ dst,
                          int* __restrict__ cur, int* __restrict__ csr) {
    for (int e = blockIdx.x * blockDim.x + threadIdx.x; e < NE; e += gridDim.x * blockDim.x) {
        int d = dst[e];
        int p = atomicAdd(&cur[d], 1);
        csr[p] = src[e];
    }
}

__global__ void k_init_st(float* __restrict__ st) {
    int t = threadIdx.x;
    st[t] = (t < DD) ? 1.f : 0.f;
}

// ---------------- aggregation: one wave per dst node ----------------
// agg'[n][c] = s[c] * sum_{j in N(n)} hraw[j][c] + t[c] * deg(n)

__global__ __launch_bounds__(256) void k_agg(const float* __restrict__ h,
                                             const int* __restrict__ off,
                                             const int* __restrict__ csr,
                                             const float* __restrict__ st,
                                             float* __restrict__ agg) {
    int w = (blockIdx.x * blockDim.x + threadIdx.x) >> 6;
    int lane = threadIdx.x & 63;
    if (w >= NN) return;
    int lo = off[w], hi = off[w + 1];
    const float2* hp = (const float2*)h;
    float2 acc = make_float2(0.f, 0.f);
    int e = lo;
    for (; e + 4 <= hi; e += 4) {
        int s0 = csr[e], s1 = csr[e + 1], s2 = csr[e + 2], s3 = csr[e + 3];
        float2 v0 = hp[(size_t)s0 * 64 + lane];
        float2 v1 = hp[(size_t)s1 * 64 + lane];
        float2 v2 = hp[(size_t)s2 * 64 + lane];
        float2 v3 = hp[(size_t)s3 * 64 + lane];
        acc.x += (v0.x + v1.x) + (v2.x + v3.x);
        acc.y += (v0.y + v1.y) + (v2.y + v3.y);
    }
    for (; e < hi; ++e) {
        int s = csr[e];
        float2 v = hp[(size_t)s * 64 + lane];
        acc.x += v.x; acc.y += v.y;
    }
    float degf = (float)(hi - lo);
    int c = lane * 2;
    float2 o;
    o.x = fmaf(st[c],     acc.x, st[DD + c]     * degf);
    o.y = fmaf(st[c + 1], acc.y, st[DD + c + 1] * degf);
    ((float2*)agg)[(size_t)w * 64 + lane] = o;
}

// ---------------- fused dual GEMM + bias + relu + column stats ----------------
// hout = relu( agg' @ Wrel + (s*hraw + t) @ Wroot + brel ), raw relu stored.
// Column sums/sumsq accumulated into stats[0..127] / stats[128..255].

__global__ __launch_bounds__(256) void k_gemm(const float* __restrict__ agg,
                                              const float* __restrict__ hraw,
                                              const float* __restrict__ st,
                                              const float* __restrict__ Wrel,
                                              const float* __restrict__ Wroot,
                                              const float* __restrict__ brel,
                                              float* __restrict__ hout,
                                              float* __restrict__ stats) {
    __shared__ float As[64][132];
    __shared__ float Bs[64][64];
    const int tid = threadIdx.x;
    const int tx = tid & 15, ty = tid >> 4;
    const int n0 = blockIdx.x * 64;
    const int c0 = blockIdx.y * 64;
    float acc[4][4] = {};
    for (int pass = 0; pass < 2; ++pass) {
        const float* A = pass ? hraw : agg;
        const float* W = pass ? Wroot : Wrel;
        if (pass) __syncthreads();  // protect As reads from pass 0
#pragma unroll
        for (int rep = 0; rep < 8; ++rep) {
            int r = rep * 8 + (tid >> 5);
            int kq = (tid & 31) * 4;
            int n = n0 + r;
            float4 v = make_float4(0.f, 0.f, 0.f, 0.f);
            if (n < NN) v = *(const float4*)(A + (size_t)n * DD + kq);
            if (pass) {
                float4 s4 = *(const float4*)(st + kq);
                float4 t4 = *(const float4*)(st + DD + kq);
                v.x = fmaf(s4.x, v.x, t4.x);
                v.y = fmaf(s4.y, v.y, t4.y);
                v.z = fmaf(s4.z, v.z, t4.z);
                v.w = fmaf(s4.w, v.w, t4.w);
            }
            *(float4*)(&As[r][kq]) = v;
        }
        for (int kc = 0; kc < DD; kc += 64) {
            __syncthreads();  // As ready / previous Bs reads done
#pragma unroll
            for (int rep = 0; rep < 4; ++rep) {
                int idx = rep * 256 + tid;
                int kl = idx >> 4;
                int j = (idx & 15) * 4;
                *(float4*)(&Bs[kl][j]) = *(const float4*)(W + (size_t)(kc + kl) * DD + c0 + j);
            }
            __syncthreads();
#pragma unroll 16
            for (int k = 0; k < 64; ++k) {
                float4 b = *(float4*)(&Bs[k][tx * 4]);
#pragma unroll
                for (int i = 0; i < 4; ++i) {
                    float a = As[ty * 4 + i][kc + k];
                    acc[i][0] = fmaf(a, b.x, acc[i][0]);
                    acc[i][1] = fmaf(a, b.y, acc[i][1]);
                    acc[i][2] = fmaf(a, b.z, acc[i][2]);
                    acc[i][3] = fmaf(a, b.w, acc[i][3]);
                }
            }
        }
    }
    float4 bias = *(const float4*)(brel + c0 + tx * 4);
    float csum[4] = {0.f, 0.f, 0.f, 0.f};
    float csq[4] = {0.f, 0.f, 0.f, 0.f};
#pragma unroll
    for (int i = 0; i < 4; ++i) {
        int n = n0 + ty * 4 + i;
        if (n < NN) {
            float4 o;
            o.x = fmaxf(acc[i][0] + bias.x, 0.f);
            o.y = fmaxf(acc[i][1] + bias.y, 0.f);
            o.z = fmaxf(acc[i][2] + bias.z, 0.f);
            o.w = fmaxf(acc[i][3] + bias.w, 0.f);
            *(float4*)(hout + (size_t)n * DD + c0 + tx * 4) = o;
            csum[0] += o.x; csum[1] += o.y; csum[2] += o.z; csum[3] += o.w;
            csq[0] += o.x * o.x; csq[1] += o.y * o.y;
            csq[2] += o.z * o.z; csq[3] += o.w * o.w;
        }
    }
    __syncthreads();  // all threads done with As/Bs reads
    *(float4*)(&As[ty][tx * 4]) = make_float4(csum[0], csum[1], csum[2], csum[3]);
    *(float4*)(&As[16 + ty][tx * 4]) = make_float4(csq[0], csq[1], csq[2], csq[3]);
    __syncthreads();
    if (tid < 128) {
        int isq = tid >> 6;       // 0 = sum, 1 = sumsq
        int cc = tid & 63;
        float s = 0.f;
#pragma unroll
        for (int r = 0; r < 16; ++r) s += As[isq * 16 + r][cc];
        atomicAdd(&stats[isq * DD + c0 + cc], s);
    }
}

__global__ void k_bn(float* __restrict__ stats, const float* __restrict__ gamma,
                     const float* __restrict__ beta, float* __restrict__ st) {
    int c = threadIdx.x;  // 128 threads
    float mean = stats[c] * (1.0f / NN);
    float var = stats[DD + c] * (1.0f / NN) - mean * mean;
    float s = gamma[c] / sqrtf(var + BN_EPS);
    st[c] = s;
    st[DD + c] = beta[c] - mean * s;
    // zero stats for the next layer's accumulation
    stats[c] = 0.f;
    stats[DD + c] = 0.f;
}

// ---------------- pooling: contiguous chunks, flush on graph change ----------------
// Accumulates RAW h sums per graph (BN applied later in k_head).

#define POOL_BLOCKS 128

__global__ __launch_bounds__(256) void k_pool(const float* __restrict__ h,
                                              const int* __restrict__ batch,
                                              float* __restrict__ pooled,
                                              float* __restrict__ counts) {
    const int c = threadIdx.x & 127;
    const int half = threadIdx.x >> 7;  // two row streams per block
    const int chunk = (NN + POOL_BLOCKS - 1) / POOL_BLOCKS;
    int lo = blockIdx.x * chunk;
    int hi = lo + chunk; if (hi > NN) hi = NN;
    float acc = 0.f;
    int cur = -1, cnt = 0;
    for (int n = lo + half; n < hi; n += 2) {
        int g = batch[n];
        float v = h[(size_t)n * DD + c];
        if (g != cur) {
            if (cur >= 0) {
                atomicAdd(&pooled[cur * DD + c], acc);
                if (c == 0) atomicAdd(&counts[cur], (float)cnt);
            }
            cur = g; acc = 0.f; cnt = 0;
        }
        acc += v; cnt++;
    }
    if (cur >= 0) {
        atomicAdd(&pooled[cur * DD + c], acc);
        if (c == 0) atomicAdd(&counts[cur], (float)cnt);
    }
}

// ---------------- head: apply BN to pooled means, dense+relu, mu ----------------

__global__ __launch_bounds__(1024) void k_head(const float* __restrict__ pooled,
                                               const float* __restrict__ counts,
                                               const float* __restrict__ st,
                                               const float* __restrict__ dw,
                                               const float* __restrict__ db,
                                               const float* __restrict__ muw,
                                               const float* __restrict__ mub,
                                               float* __restrict__ out) {
    __shared__ float pm[NG][DD];
    __shared__ float zs[NG][DD];
    int t = threadIdx.x;
    int g = t >> 7, c = t & 127;
    float cntg = counts[g];
    // mean over graph of BN(h) = (s * sum_raw + t * count) / max(count,1)
    pm[g][c] = fmaf(st[c], pooled[g * DD + c], st[DD + c] * cntg) / fmaxf(cntg, 1.0f);
    __syncthreads();
    float acc = 0.f;
    for (int k = 0; k < DD; ++k)
        acc = fmaf(pm[g][k], dw[k * DD + c], acc);
    float z = fmaxf(acc + db[c], 0.f);
    zs[g][c] = z * muw[c];
    __syncthreads();
    if (c == 0) {
        float s = 0.f;
        for (int k = 0; k < DD; ++k) s += zs[g][k];
        out[g] = s + mub[0];
    }
}

// ---------------- host ----------------

extern "C" void kernel_launch(void* const* d_in, const int* in_sizes, int n_in,
                              void* d_out, int out_size, void* d_ws, size_t ws_size,
                              hipStream_t stream) {
    const float* x      = (const float*)d_in[0];
    const int*   ei     = (const int*)d_in[1];
    const int*   batch  = (const int*)d_in[2];
    const float* W_rel  = (const float*)d_in[3];
    const float* b_rel  = (const float*)d_in[4];
    const float* W_root = (const float*)d_in[5];
    const float* gamma  = (const float*)d_in[6];
    const float* beta   = (const float*)d_in[7];
    const float* dw     = (const float*)d_in[8];
    const float* db     = (const float*)d_in[9];
    const float* muw    = (const float*)d_in[10];
    const float* mub    = (const float*)d_in[11];
    float* out = (float*)d_out;

    char* w = (char*)d_ws;
    auto alloc = [&](size_t bytes) {
        char* p = w;
        w += (bytes + 255) & ~(size_t)255;
        return p;
    };
    int*   deg    = (int*)alloc((size_t)NN * 4);
    int*   off    = (int*)alloc((size_t)(NN + 1) * 4);
    int*   cur    = (int*)alloc((size_t)NN * 4);
    int*   csr    = (int*)alloc((size_t)NE * 4);
    float* hA     = (float*)alloc((size_t)NN * DD * 4);
    float* hB     = (float*)alloc((size_t)NN * DD * 4);
    float* aggb   = (float*)alloc((size_t)NN * DD * 4);
    float* stats  = (float*)alloc(2 * DD * 4);
    float* st     = (float*)alloc(2 * DD * 4);
    float* pooled = (float*)alloc(NG * DD * 4);
    float* counts = (float*)alloc(NG * 4);

    const int* src = ei;
    const int* dst = ei + NE;

    hipMemsetAsync(deg, 0, (size_t)NN * 4, stream);
    hipMemsetAsync(stats, 0, 2 * DD * 4, stream);
    k_hist<<<2048, 256, 0, stream>>>(dst, deg);
    k_scan<<<1, 1024, 0, stream>>>(deg, off, cur);
    k_scatter<<<2048, 256, 0, stream>>>(src, dst, cur, csr);
    k_init_st<<<1, 256, 0, stream>>>(st);

    const float* hcur = x;
    float* bufs[2] = {hA, hB};
    for (int i = 0; i < NLAYERS; ++i) {
        float* hnext = bufs[i & 1];
        k_agg<<<(NN * 64 + 255) / 256, 256, 0, stream>>>(hcur, off, csr, st, aggb);
        k_gemm<<<dim3((NN + 63) / 64, 2), 256, 0, stream>>>(
            aggb, hcur, st, W_rel + (size_t)i * DD * DD, W_root + (size_t)i * DD * DD,
            b_rel + (size_t)i * DD, hnext, stats);
        k_bn<<<1, 128, 0, stream>>>(stats, gamma + (size_t)i * DD, beta + (size_t)i * DD, st);
        hcur = hnext;
    }
    hipMemsetAsync(pooled, 0, (size_t)NG * DD * 4, stream);
    hipMemsetAsync(counts, 0, (size_t)NG * 4, stream);
    k_pool<<<POOL_BLOCKS, 256, 0, stream>>>(hcur, batch, pooled, counts);
    k_head<<<1, 1024, 0, stream>>>(pooled, counts, st, dw, db, muw, mub, out);
}